// Round 18
// baseline (202.948 us; speedup 1.0000x reference)
//
#include <hip/hip_runtime.h>
#include <hip/hip_bf16.h>

typedef unsigned short u16;
typedef unsigned int u32;
typedef __attribute__((ext_vector_type(8))) short bf16x8;
typedef __attribute__((ext_vector_type(8))) unsigned short u16x8;
typedef __attribute__((ext_vector_type(4))) unsigned short u16x4;
typedef __attribute__((ext_vector_type(4))) float f32x4;

#define DEVI __device__ __forceinline__

static constexpr int Bn = 8, Tn = 1024, Fn = 1024, Hn = 16, DKn = 64;
static constexpr int Mtot = Bn * Tn;  // 8192

DEVI u16 f2bf(float x) {
  unsigned u = __builtin_bit_cast(unsigned, x);
  u += 0x7fffu + ((u >> 16) & 1u);
  return (u16)(u >> 16);
}

DEVI u32 cvt_pk_bf16(float lo, float hi) {
  u32 r;
  asm("v_cvt_pk_bf16_f32 %0, %1, %2" : "=v"(r) : "v"(lo), "v"(hi));
  return r;
}

DEVI float fast_exp2(float x) { return __builtin_amdgcn_exp2f(x); }  // bare v_exp_f32

DEVI f32x4 mfma16(bf16x8 a, bf16x8 b, f32x4 c) {
  return __builtin_amdgcn_mfma_f32_16x16x32_bf16(a, b, c, 0, 0, 0);
}

typedef const __attribute__((address_space(1))) void GAS;
typedef __attribute__((address_space(3))) void LAS;
#define GLL16(gp, lp) __builtin_amdgcn_global_load_lds((GAS*)(gp), (LAS*)(lp), 16, 0, 0)

// ---------------- fp32 -> bf16 conversion (weights only; X is fused into GEMM) ----------------
DEVI void cvt_chunk(const float* __restrict__ in, u16* __restrict__ out, int i) {
  const float4* p = reinterpret_cast<const float4*>(in + i);
  float4 a = p[0], b = p[1];
  float v[8] = {a.x, a.y, a.z, a.w, b.x, b.y, b.z, b.w};
  u16x8 r;
#pragma unroll
  for (int j = 0; j < 8; j++) r[j] = f2bf(v[j]);
  *reinterpret_cast<u16x8*>(out + i) = r;
}

__global__ __launch_bounds__(256) void cvt4(const float* __restrict__ a, const float* __restrict__ b,
                                            const float* __restrict__ c, const float* __restrict__ e,
                                            u16* __restrict__ oa, u16* __restrict__ ob,
                                            u16* __restrict__ oc, u16* __restrict__ oe) {
  const int id = blockIdx.x * 256 + threadIdx.x;
  const int seg = id >> 17;
  const int off = (id & 131071) * 8;
  const float* s = seg == 0 ? a : (seg == 1 ? b : (seg == 2 ? c : e));
  u16* d = seg == 0 ? oa : (seg == 1 ? ob : (seg == 2 ? oc : oe));
  cvt_chunk(s, d, off);
}

// ============ m97-replica projection GEMM: 128x128, BK=32, LINEAR LDS, fused cvt ============
// The measured-good recipe (m97/m103: 874-912 TF): 128^2 tile, BK=32, LINEAR LDS
// (no swizzle -- m97 measured its peak without one), GLL B-staging, 2-barrier loop,
// 32KB LDS -> 4 blocks/CU co-resident (the m114 mechanism: other blocks' waves
// fill barrier/vmcnt stalls; every BK=64 variant was 64-96KB -> 1-2 blocks and
// plateaued at ~660 TF).
// Per K-tile t: {loadA(t+1) 4x dwordx4 fp32 -> regs; stageB(t+1) 2x GLL;
// vmcnt(6) lgkmcnt(0)} -> s_barrier -> {8x ds_read_b128, 16 MFMA} ->
// writeA(t+1): 8 cvt_pk + 4 ds_write_b64 (linear) -> s_barrier.
// vmcnt(6): queue=[B(t)x2 old, A(t+1)x4, B(t+1)x2] -> drains exactly B(t);
// compiler auto-waits the A regs at writeA. lgkmcnt(0) drains own ds_writes
// (per-wave counters, R8 lesson); barrier AFTER waits, BEFORE any ds_read.
// MODE 0: bf16 (B,H,T,DK), swapped acc (rows=n), oscale. MODE 1: bf16 V^T.
template <int MODE>
__global__ __launch_bounds__(256, 1) void gemm8f(const float* __restrict__ A,
                                                 const u16* __restrict__ Bw,
                                                 const float* __restrict__ bias,
                                                 u16* __restrict__ Obf,
                                                 float oscale) {
  constexpr int Kd = 1024;
  __shared__ u16 sA[2][128 * 32];
  __shared__ u16 sB[2][128 * 32];
  const int tid = threadIdx.x;
  const int l = tid & 63, w = tid >> 6;
  const int wm = w >> 1, wn = w & 1;
  const int lr = l & 15, g = l >> 4;
  const int bid = blockIdx.x;
  const int wg = (bid & 7) * 64 + (bid >> 3);  // bijective XCD swizzle (512%8==0)
  const int m0 = (wg >> 3) * 128, n0 = (wg & 7) * 128;

  f32x4 acc[4][4];
#pragma unroll
  for (int i = 0; i < 4; i++)
#pragma unroll
    for (int j = 0; j < 4; j++) acc[i][j] = f32x4{0.f, 0.f, 0.f, 0.f};

  // A fp32 tile 128x32 = 16KB: chunk c = i*256+tid -> row r=c>>3, quad q=c&7
  int aoffF[4], awb[4];
#pragma unroll
  for (int i = 0; i < 4; i++) {
    const int c = i * 256 + tid;
    const int r = c >> 3, q = c & 7;
    aoffF[i] = r * Kd + q * 4;
    awb[i] = r * 64 + q * 8;  // linear bf16 dest (8B per chunk)
  }
  // B bf16 tile 128x32 = 8KB: chunk c = i*256+tid -> row r=c>>2, slot s=c&3
  int boff[2];
#pragma unroll
  for (int i = 0; i < 2; i++) {
    const int c = i * 256 + tid;
    boff[i] = (c >> 2) * Kd + (c & 3) * 8;
  }
  const float* Af = A + (size_t)m0 * Kd;
  const u16* Bbase = Bw + (size_t)n0 * Kd;

  float4 ra[4];
  auto loadA = [&](int kt) {
#pragma unroll
    for (int i = 0; i < 4; i++)
      ra[i] = *reinterpret_cast<const float4*>(Af + kt * 32 + aoffF[i]);
  };
  auto writeA = [&](int buf) {
#pragma unroll
    for (int i = 0; i < 4; i++) {
      uint2 pk;
      pk.x = cvt_pk_bf16(ra[i].x, ra[i].y);
      pk.y = cvt_pk_bf16(ra[i].z, ra[i].w);
      *reinterpret_cast<uint2*>((char*)&sA[buf][0] + awb[i]) = pk;
    }
  };
  auto stageB = [&](int buf, int kt) {
#pragma unroll
    for (int i = 0; i < 2; i++)
      GLL16(Bbase + kt * 32 + boff[i], (char*)&sB[buf][0] + (i * 256 + w * 64) * 16);
  };

  loadA(0);
  stageB(0, 0);
  writeA(0);  // compiler inserts vmcnt for A regs
  for (int t = 0; t < 32; ++t) {
    const int cur = t & 1;
    if (t < 31) {
      loadA(t + 1);
      stageB(cur ^ 1, t + 1);
      asm volatile("s_waitcnt vmcnt(6) lgkmcnt(0)" ::: "memory");
    } else {
      asm volatile("s_waitcnt vmcnt(0) lgkmcnt(0)" ::: "memory");
    }
    asm volatile("s_barrier" ::: "memory");  // all waves' tile-t staging visible
    bf16x8 af[4], bfr[4];
#pragma unroll
    for (int mi = 0; mi < 4; mi++)
      af[mi] = *reinterpret_cast<const bf16x8*>(
          (const char*)&sA[cur][0] + (wm * 64 + mi * 16 + lr) * 64 + g * 16);
#pragma unroll
    for (int ni = 0; ni < 4; ni++)
      bfr[ni] = *reinterpret_cast<const bf16x8*>(
          (const char*)&sB[cur][0] + (wn * 64 + ni * 16 + lr) * 64 + g * 16);
    __builtin_amdgcn_s_setprio(1);
#pragma unroll
    for (int mi = 0; mi < 4; mi++)
#pragma unroll
      for (int ni = 0; ni < 4; ni++) {
        if constexpr (MODE == 1)
          acc[mi][ni] = mfma16(af[mi], bfr[ni], acc[mi][ni]);
        else
          acc[ni][mi] = mfma16(bfr[ni], af[mi], acc[ni][mi]);
      }
    __builtin_amdgcn_s_setprio(0);
    if (t < 31) writeA(cur ^ 1);             // writes buf not read this tile
    asm volatile("s_barrier" ::: "memory");  // reads of tile t done before overwrite
  }

  if constexpr (MODE == 1) {
    // V^T (B,H,DK,T): rows=m via (g,j) -> u16x4 along t
#pragma unroll
    for (int ni = 0; ni < 4; ni++) {
      const int n = n0 + wn * 64 + ni * 16 + lr;
      const float bv = bias[n];
      const int h = n >> 6, dk = n & 63;
#pragma unroll
      for (int mi = 0; mi < 4; mi++) {
        const int mb = m0 + wm * 64 + mi * 16 + g * 4;
        u16x4 pk;
#pragma unroll
        for (int j = 0; j < 4; j++) pk[j] = f2bf(acc[mi][ni][j] + bv);
        const int b = mb >> 10, tt = mb & 1023;
        size_t idx = (((size_t)b * 16 + h) * 64 + dk) * 1024 + tt;
        *reinterpret_cast<u16x4*>(Obf + idx) = pk;
      }
    }
  } else {
    // (B,H,T,DK): rows=n via (g,j) -> 4 consecutive dk per lane
#pragma unroll
    for (int ni = 0; ni < 4; ni++) {
      const int nb = n0 + wn * 64 + ni * 16 + g * 4;
      const float4 b4 = *reinterpret_cast<const float4*>(&bias[nb]);
#pragma unroll
      for (int mi = 0; mi < 4; mi++) {
        const int m = m0 + wm * 64 + mi * 16 + lr;
        const f32x4 a = acc[ni][mi];
        const int b = m >> 10, tt = m & 1023;
        const int h = nb >> 6, dk0 = nb & 63;
        u16x4 pk;
        pk[0] = f2bf((a[0] + b4.x) * oscale);
        pk[1] = f2bf((a[1] + b4.y) * oscale);
        pk[2] = f2bf((a[2] + b4.z) * oscale);
        pk[3] = f2bf((a[3] + b4.w) * oscale);
        *reinterpret_cast<u16x4*>(&Obf[((((size_t)b * 16 + h) * 1024 + tt) * 64) + dk0]) = pk;
      }
    }
  }
}

// ---------------- out-projection: 128x128, BK=32, linear LDS, all-GLL ----------------
// stage(t+1) = A2+B2 GLL -> vmcnt(4) (drains tile t's 4, leaves next 4 in flight)
// -> barrier -> {ds_read, 16 MFMA} -> barrier. 32KB LDS -> 4-5 blocks/CU.
__global__ __launch_bounds__(256, 1) void gemm_out(const u16* __restrict__ A,
                                                   const u16* __restrict__ Bw,
                                                   const float* __restrict__ bias,
                                                   const float* __restrict__ mask,
                                                   float* __restrict__ Of) {
  constexpr int Kd = 1024;
  __shared__ u16 sA[2][128 * 32];
  __shared__ u16 sB[2][128 * 32];
  const int tid = threadIdx.x;
  const int l = tid & 63, w = tid >> 6;
  const int wm = w >> 1, wn = w & 1;
  const int lr = l & 15, g = l >> 4;
  const int bid = blockIdx.x;
  const int wg = (bid & 7) * 64 + (bid >> 3);
  const int m0 = (wg >> 3) * 128, n0 = (wg & 7) * 128;

  f32x4 acc[4][4];
#pragma unroll
  for (int i = 0; i < 4; i++)
#pragma unroll
    for (int j = 0; j < 4; j++) acc[i][j] = f32x4{0.f, 0.f, 0.f, 0.f};

  int off2[2];
#pragma unroll
  for (int i = 0; i < 2; i++) {
    const int c = i * 256 + tid;
    off2[i] = (c >> 2) * Kd + (c & 3) * 8;
  }
  const u16* Abase = A + (size_t)m0 * Kd;
  const u16* Bbase = Bw + (size_t)n0 * Kd;

  auto stage = [&](int buf, int kt) {
#pragma unroll
    for (int i = 0; i < 2; i++)
      GLL16(Abase + kt * 32 + off2[i], (char*)&sA[buf][0] + (i * 256 + w * 64) * 16);
#pragma unroll
    for (int i = 0; i < 2; i++)
      GLL16(Bbase + kt * 32 + off2[i], (char*)&sB[buf][0] + (i * 256 + w * 64) * 16);
  };

  stage(0, 0);
  for (int t = 0; t < 32; ++t) {
    const int cur = t & 1;
    if (t < 31) {
      stage(cur ^ 1, t + 1);
      asm volatile("s_waitcnt vmcnt(4)" ::: "memory");
    } else {
      asm volatile("s_waitcnt vmcnt(0)" ::: "memory");
    }
    asm volatile("s_barrier" ::: "memory");
    bf16x8 af[4], bfr[4];
#pragma unroll
    for (int mi = 0; mi < 4; mi++)
      af[mi] = *reinterpret_cast<const bf16x8*>(
          (const char*)&sA[cur][0] + (wm * 64 + mi * 16 + lr) * 64 + g * 16);
#pragma unroll
    for (int ni = 0; ni < 4; ni++)
      bfr[ni] = *reinterpret_cast<const bf16x8*>(
          (const char*)&sB[cur][0] + (wn * 64 + ni * 16 + lr) * 64 + g * 16);
    __builtin_amdgcn_s_setprio(1);
#pragma unroll
    for (int mi = 0; mi < 4; mi++)
#pragma unroll
      for (int ni = 0; ni < 4; ni++) acc[ni][mi] = mfma16(bfr[ni], af[mi], acc[ni][mi]);
    __builtin_amdgcn_s_setprio(0);
    asm volatile("s_barrier" ::: "memory");
  }

#pragma unroll
  for (int ni = 0; ni < 4; ni++) {
    const int nb = n0 + wn * 64 + ni * 16 + g * 4;
    const float4 b4 = *reinterpret_cast<const float4*>(&bias[nb]);
#pragma unroll
    for (int mi = 0; mi < 4; mi++) {
      const int m = m0 + wm * 64 + mi * 16 + lr;
      const f32x4 a = acc[ni][mi];
      const float mk = mask[m];
      float4 o;
      o.x = (a[0] + b4.x) * mk;
      o.y = (a[1] + b4.y) * mk;
      o.z = (a[2] + b4.z) * mk;
      o.w = (a[3] + b4.w) * mk;
      *reinterpret_cast<float4*>(&Of[(size_t)m * 1024 + nb]) = o;
    }
  }
}

// ---------------- flash attention (R17: 8 waves x 32 q-rows, grid 512) ----------------
__global__ __launch_bounds__(512, 1) void flash_attn(const u16* __restrict__ Qb,
                                                     const u16* __restrict__ Kb,
                                                     const u16* __restrict__ Vt,
                                                     u16* __restrict__ ctx) {
  __shared__ u16 sK[2][64 * 64];
  __shared__ u16 sV[64 * 64];
  __shared__ u16 pbuf[8][16 * 64];
  const int tid = threadIdx.x, l = tid & 63, w = tid >> 6;
  const int lr = l & 15, g = l >> 4;
  const int wg = ((blockIdx.x & 7) << 6) + (blockIdx.x >> 3);  // bijective (512%8==0)
  const int qt = wg & 3, bh = wg >> 2;
  const u16* Qh = Qb + (size_t)bh * (Tn * DKn);
  const u16* Kh = Kb + (size_t)bh * (Tn * DKn);
  const u16* Vh = Vt + (size_t)bh * (Tn * DKn);

  bf16x8 aq[2][2];
  int qrow[2];
#pragma unroll
  for (int qg = 0; qg < 2; qg++) {
    qrow[qg] = qt * 256 + w * 32 + qg * 16 + lr;
    aq[qg][0] = *reinterpret_cast<const bf16x8*>(Qh + (size_t)qrow[qg] * 64 + g * 8);
    aq[qg][1] = *reinterpret_cast<const bf16x8*>(Qh + (size_t)qrow[qg] * 64 + 32 + g * 8);
  }

  float mrow[2] = {-1e30f, -1e30f}, lsum[2] = {0.f, 0.f};
  f32x4 of[2][4];
#pragma unroll
  for (int qg = 0; qg < 2; qg++)
#pragma unroll
    for (int c = 0; c < 4; c++) of[qg][c] = f32x4{0.f, 0.f, 0.f, 0.f};

  char* pb = (char*)&pbuf[w][0];
  const int sw = (lr & 7) << 4;
  int wadr[4];
#pragma unroll
  for (int c = 0; c < 4; c++) wadr[c] = lr * 128 + (((c * 16 + g * 4) * 2) ^ sw);
  const int radr0 = lr * 128 + ((g * 16) ^ sw);
  const int radr1 = lr * 128 + ((64 + g * 16) ^ sw);

  const int sr = tid >> 3;
  const int sc = (tid & 7) ^ (sr & 7);
  auto stageK = [&](int buf, int kv0) {
    GLL16((const char*)Kh + ((size_t)(kv0 + sr) << 7) + (sc << 4),
          (char*)&sK[buf][0] + w * 1024);
  };
  auto stageV = [&](int kv0) {
    GLL16((const char*)Vh + ((size_t)sr << 11) + kv0 * 2 + (sc << 4),
          (char*)&sV[0] + w * 1024);
  };

  stageK(0, 0);
  stageV(0);
  __syncthreads();
  int cur = 0;

  for (int t = 0; t < 16; t++) {
    if (t < 15) stageK(cur ^ 1, (t + 1) * 64);
    const char* kb = (const char*)&sK[cur][0];
    const char* vb = (const char*)&sV[0];

    f32x4 sf[2][4];
    __builtin_amdgcn_s_setprio(1);
#pragma unroll
    for (int c = 0; c < 4; c++) {
      const char* kr = kb + (c * 16 + lr) * 128;
      bf16x8 k0 = *reinterpret_cast<const bf16x8*>(kr + ((g * 16) ^ sw));
      bf16x8 k1 = *reinterpret_cast<const bf16x8*>(kr + ((64 + g * 16) ^ sw));
      f32x4 z0 = mfma16(k0, aq[0][0], f32x4{0.f, 0.f, 0.f, 0.f});
      sf[0][c] = mfma16(k1, aq[0][1], z0);
      f32x4 z1 = mfma16(k0, aq[1][0], f32x4{0.f, 0.f, 0.f, 0.f});
      sf[1][c] = mfma16(k1, aq[1][1], z1);
    }
    __builtin_amdgcn_s_setprio(0);

    bf16x8 ap[2][2];
#pragma unroll
    for (int qg = 0; qg < 2; qg++) {
      f32x4 mx4 = sf[qg][0];
#pragma unroll
      for (int c = 1; c < 4; c++)
#pragma unroll
        for (int j = 0; j < 4; j++) mx4[j] = fmaxf(mx4[j], sf[qg][c][j]);
      const float pmax = fmaxf(fmaxf(mx4[0], mx4[1]), fmaxf(mx4[2], mx4[3]));
      if (__any(pmax > mrow[qg] + 8.0f)) {
        float mx = pmax;
        mx = fmaxf(mx, __shfl_xor(mx, 16));
        mx = fmaxf(mx, __shfl_xor(mx, 32));
        const float mn = fmaxf(mrow[qg], mx);
        const float alpha = fast_exp2(mrow[qg] - mn);
        mrow[qg] = mn;
        lsum[qg] *= alpha;
#pragma unroll
        for (int c = 0; c < 4; c++)
#pragma unroll
          for (int j = 0; j < 4; j++) of[qg][c][j] *= alpha;
      }
      const float mn = mrow[qg];
      float rs = 0.f;
#pragma unroll
      for (int c = 0; c < 4; c++)
#pragma unroll
        for (int j = 0; j < 4; j++) {
          float pp = fast_exp2(sf[qg][c][j] - mn);
          sf[qg][c][j] = pp;
          rs += pp;
        }
      lsum[qg] += rs;

#pragma unroll
      for (int c = 0; c < 4; c++) {
        uint2 pk;
        pk.x = cvt_pk_bf16(sf[qg][c][0], sf[qg][c][1]);
        pk.y = cvt_pk_bf16(sf[qg][c][2], sf[qg][c][3]);
        *reinterpret_cast<uint2*>(pb + wadr[c]) = pk;
      }
      ap[qg][0] = *reinterpret_cast<const bf16x8*>(pb + radr0);
      ap[qg][1] = *reinterpret_cast<const bf16x8*>(pb + radr1);
    }

    __syncthreads();  // B1: sV(t) writes drained & visible

    __builtin_amdgcn_s_setprio(1);
#pragma unroll
    for (int d0 = 0; d0 < 4; d0++) {
      const char* vr = vb + (d0 * 16 + lr) * 128;
      bf16x8 v0 = *reinterpret_cast<const bf16x8*>(vr + ((g * 16) ^ sw));
      bf16x8 v1 = *reinterpret_cast<const bf16x8*>(vr + ((64 + g * 16) ^ sw));
#pragma unroll
      for (int qg = 0; qg < 2; qg++) {
        f32x4 z = mfma16(v0, ap[qg][0], of[qg][d0]);
        of[qg][d0] = mfma16(v1, ap[qg][1], z);
      }
    }
    __builtin_amdgcn_s_setprio(0);

    __syncthreads();  // B2: all waves done reading sV(t)/sK[cur]
    if (t < 15) stageV((t + 1) * 64);
    cur ^= 1;
  }

  const int b = bh >> 4, h = bh & 15;
#pragma unroll
  for (int qg = 0; qg < 2; qg++) {
    float ls = lsum[qg];
    ls += __shfl_xor(ls, 16);
    ls += __shfl_xor(ls, 32);
    const float inv = 1.0f / ls;
    const size_t base = ((size_t)b * 1024 + qrow[qg]) * 1024 + h * 64;
#pragma unroll
    for (int d0 = 0; d0 < 4; d0++) {
      uint2 pk;
      pk.x = cvt_pk_bf16(of[qg][d0][0] * inv, of[qg][d0][1] * inv);
      pk.y = cvt_pk_bf16(of[qg][d0][2] * inv, of[qg][d0][3] * inv);
      *reinterpret_cast<uint2*>(ctx + base + d0 * 16 + g * 4) = pk;
    }
  }
}

// ---------------- launch ----------------
extern "C" void kernel_launch(void* const* d_in, const int* in_sizes, int n_in,
                              void* d_out, int out_size, void* d_ws, size_t ws_size,
                              hipStream_t stream) {
  const float* query = (const float*)d_in[0];
  const float* key = (const float*)d_in[1];
  const float* value = (const float*)d_in[2];
  const float* mask = (const float*)d_in[3];
  const float* Wq = (const float*)d_in[4];
  const float* bq = (const float*)d_in[5];
  const float* Wk = (const float*)d_in[6];
  const float* bk = (const float*)d_in[7];
  const float* Wv = (const float*)d_in[8];
  const float* bv = (const float*)d_in[9];
  const float* Wo = (const float*)d_in[10];
  const float* bo = (const float*)d_in[11];
  (void)in_sizes; (void)n_in; (void)out_size; (void)ws_size;

  u16* ws = (u16*)d_ws;
  const size_t MB8 = (size_t)8 << 20;  // 8M u16 = 16 MB
  u16* ctx = ws;
  u16* Wqb = ws + 3 * MB8;
  u16* Wkb = Wqb + (1 << 20);
  u16* Wvb = Wkb + (1 << 20);
  u16* Wob = Wvb + (1 << 20);
  u16* Qb = Wob + (1 << 20);
  u16* Kb = Qb + MB8;
  u16* Vtb = Kb + MB8;

  cvt4<<<2048, 256, 0, stream>>>(Wq, Wk, Wv, Wo, Wqb, Wkb, Wvb, Wob);

  const float SC = 0.125f * 1.44269504089f;  // 1/sqrt(DK) * log2(e)
  const int ng = (Mtot / 128) * (Fn / 128);  // 512 blocks
  gemm8f<0><<<ng, 256, 0, stream>>>(query, Wqb, bq, Qb, SC);
  gemm8f<0><<<ng, 256, 0, stream>>>(key, Wkb, bk, Kb, 1.0f);
  gemm8f<1><<<ng, 256, 0, stream>>>(value, Wvb, bv, Vtb, 1.0f);

  flash_attn<<<Bn * Hn * (Tn / 256), 512, 0, stream>>>(Qb, Kb, Vtb, ctx);

  gemm_out<<<ng, 256, 0, stream>>>(ctx, Wob, bo, mask, (float*)d_out);
}

// Round 19
// 173.533 us; speedup vs baseline: 1.1695x; 1.1695x over previous
//
#include <hip/hip_runtime.h>
#include <hip/hip_bf16.h>

typedef unsigned short u16;
typedef unsigned int u32;
typedef __attribute__((ext_vector_type(8))) short bf16x8;
typedef __attribute__((ext_vector_type(8))) unsigned short u16x8;
typedef __attribute__((ext_vector_type(4))) unsigned short u16x4;
typedef __attribute__((ext_vector_type(4))) float f32x4;

#define DEVI __device__ __forceinline__

static constexpr int Bn = 8, Tn = 1024, Fn = 1024, Hn = 16, DKn = 64;
static constexpr int Mtot = Bn * Tn;  // 8192

DEVI u16 f2bf(float x) {
  unsigned u = __builtin_bit_cast(unsigned, x);
  u += 0x7fffu + ((u >> 16) & 1u);
  return (u16)(u >> 16);
}

DEVI u32 cvt_pk_bf16(float lo, float hi) {
  u32 r;
  asm("v_cvt_pk_bf16_f32 %0, %1, %2" : "=v"(r) : "v"(lo), "v"(hi));
  return r;
}

DEVI float fast_exp2(float x) { return __builtin_amdgcn_exp2f(x); }  // bare v_exp_f32

DEVI f32x4 mfma16(bf16x8 a, bf16x8 b, f32x4 c) {
  return __builtin_amdgcn_mfma_f32_16x16x32_bf16(a, b, c, 0, 0, 0);
}

typedef const __attribute__((address_space(1))) void GAS;
typedef __attribute__((address_space(3))) void LAS;
#define GLL16(gp, lp) __builtin_amdgcn_global_load_lds((GAS*)(gp), (LAS*)(lp), 16, 0, 0)

// ---------------- fp32 -> bf16 conversion (weights only; X is fused into GEMM) ----------------
DEVI void cvt_chunk(const float* __restrict__ in, u16* __restrict__ out, int i) {
  const float4* p = reinterpret_cast<const float4*>(in + i);
  float4 a = p[0], b = p[1];
  float v[8] = {a.x, a.y, a.z, a.w, b.x, b.y, b.z, b.w};
  u16x8 r;
#pragma unroll
  for (int j = 0; j < 8; j++) r[j] = f2bf(v[j]);
  *reinterpret_cast<u16x8*>(out + i) = r;
}

__global__ __launch_bounds__(256) void cvt4(const float* __restrict__ a, const float* __restrict__ b,
                                            const float* __restrict__ c, const float* __restrict__ e,
                                            u16* __restrict__ oa, u16* __restrict__ ob,
                                            u16* __restrict__ oc, u16* __restrict__ oe) {
  const int id = blockIdx.x * 256 + threadIdx.x;
  const int seg = id >> 17;
  const int off = (id & 131071) * 8;
  const float* s = seg == 0 ? a : (seg == 1 ? b : (seg == 2 ? c : e));
  u16* d = seg == 0 ? oa : (seg == 1 ? ob : (seg == 2 ? oc : oe));
  cvt_chunk(s, d, off);
}

// ============ 128x128 BK=64 fused-convert projection GEMM (R16/R17-proven best) ============
template <int MODE>
__global__ __launch_bounds__(256, 1) void gemm8f(const float* __restrict__ A,
                                                 const u16* __restrict__ Bw,
                                                 const float* __restrict__ bias,
                                                 u16* __restrict__ Obf,
                                                 float oscale) {
  constexpr int Kd = 1024;
  __shared__ u16 sA[2][128 * 64];
  __shared__ u16 sB[2][128 * 64];
  const int tid = threadIdx.x;
  const int l = tid & 63, w = tid >> 6;
  const int wm = w >> 1, wn = w & 1;
  const int lr = l & 15, g = l >> 4;
  const int bid = blockIdx.x;
  const int wg = (bid & 7) * 64 + (bid >> 3);  // bijective XCD swizzle (512%8==0)
  const int m0 = (wg >> 3) * 128, n0 = (wg & 7) * 128;

  f32x4 acc[4][4];
#pragma unroll
  for (int i = 0; i < 4; i++)
#pragma unroll
    for (int j = 0; j < 4; j++) acc[i][j] = f32x4{0.f, 0.f, 0.f, 0.f};

  int aoffF[4], awb[4];
#pragma unroll
  for (int i = 0; i < 4; i++) {
    const int c = i * 256 + tid;
    const int r = c >> 3, cc = c & 7;
    aoffF[i] = r * Kd + cc * 8;
    awb[i] = r * 128 + ((cc ^ (r & 7)) << 4);
  }
  int boff[4];
#pragma unroll
  for (int i = 0; i < 4; i++) {
    const int c = i * 256 + tid;
    const int r = c >> 3, cc = (c & 7) ^ (r & 7);
    boff[i] = r * Kd + cc * 8;
  }
  const float* Af = A + (size_t)m0 * Kd;
  const u16* Bbase = Bw + (size_t)n0 * Kd;

  float4 ra[4][2];
  auto loadA = [&](int kt) {
#pragma unroll
    for (int i = 0; i < 4; i++) {
      const float* s = Af + kt * 64 + aoffF[i];
      ra[i][0] = *reinterpret_cast<const float4*>(s);
      ra[i][1] = *reinterpret_cast<const float4*>(s + 4);
    }
  };
  auto writeA = [&](int buf) {
#pragma unroll
    for (int i = 0; i < 4; i++) {
      uint4 pk;
      pk.x = cvt_pk_bf16(ra[i][0].x, ra[i][0].y);
      pk.y = cvt_pk_bf16(ra[i][0].z, ra[i][0].w);
      pk.z = cvt_pk_bf16(ra[i][1].x, ra[i][1].y);
      pk.w = cvt_pk_bf16(ra[i][1].z, ra[i][1].w);
      *reinterpret_cast<uint4*>((char*)&sA[buf][0] + awb[i]) = pk;
    }
  };
  auto stageB = [&](int buf, int kt) {
#pragma unroll
    for (int i = 0; i < 4; i++)
      GLL16(Bbase + kt * 64 + boff[i], (char*)&sB[buf][0] + (i * 256 + w * 64) * 16);
  };

  loadA(0);
  stageB(0, 0);
  writeA(0);
  for (int t = 0; t < 16; ++t) {
    const int cur = t & 1;
    if (t < 15) {
      loadA(t + 1);
      stageB(cur ^ 1, t + 1);
      asm volatile("s_waitcnt vmcnt(12) lgkmcnt(0)" ::: "memory");
    } else {
      asm volatile("s_waitcnt vmcnt(0) lgkmcnt(0)" ::: "memory");
    }
    asm volatile("s_barrier" ::: "memory");
#pragma unroll
    for (int ks = 0; ks < 2; ks++) {
      bf16x8 af[4], bfr[4];
#pragma unroll
      for (int mi = 0; mi < 4; mi++) {
        const int row = wm * 64 + mi * 16 + lr;
        af[mi] = *reinterpret_cast<const bf16x8*>(
            (const char*)&sA[cur][0] + row * 128 + ((ks * 64 + g * 16) ^ ((row & 7) << 4)));
      }
#pragma unroll
      for (int ni = 0; ni < 4; ni++) {
        const int row = wn * 64 + ni * 16 + lr;
        bfr[ni] = *reinterpret_cast<const bf16x8*>(
            (const char*)&sB[cur][0] + row * 128 + ((ks * 64 + g * 16) ^ ((row & 7) << 4)));
      }
      __builtin_amdgcn_s_setprio(1);
#pragma unroll
      for (int mi = 0; mi < 4; mi++)
#pragma unroll
        for (int ni = 0; ni < 4; ni++) {
          if constexpr (MODE == 1)
            acc[mi][ni] = mfma16(af[mi], bfr[ni], acc[mi][ni]);
          else
            acc[ni][mi] = mfma16(bfr[ni], af[mi], acc[ni][mi]);
        }
      __builtin_amdgcn_s_setprio(0);
    }
    if (t < 15) writeA(cur ^ 1);
    asm volatile("s_barrier" ::: "memory");
  }

  if constexpr (MODE == 1) {
#pragma unroll
    for (int ni = 0; ni < 4; ni++) {
      const int n = n0 + wn * 64 + ni * 16 + lr;
      const float bv = bias[n];
      const int h = n >> 6, dk = n & 63;
#pragma unroll
      for (int mi = 0; mi < 4; mi++) {
        const int mb = m0 + wm * 64 + mi * 16 + g * 4;
        u16x4 pk;
#pragma unroll
        for (int j = 0; j < 4; j++) pk[j] = f2bf(acc[mi][ni][j] + bv);
        const int b = mb >> 10, tt = mb & 1023;
        size_t idx = (((size_t)b * 16 + h) * 64 + dk) * 1024 + tt;
        *reinterpret_cast<u16x4*>(Obf + idx) = pk;
      }
    }
  } else {
#pragma unroll
    for (int ni = 0; ni < 4; ni++) {
      const int nb = n0 + wn * 64 + ni * 16 + g * 4;
      const float4 b4 = *reinterpret_cast<const float4*>(&bias[nb]);
#pragma unroll
      for (int mi = 0; mi < 4; mi++) {
        const int m = m0 + wm * 64 + mi * 16 + lr;
        const f32x4 a = acc[ni][mi];
        const int b = m >> 10, tt = m & 1023;
        const int h = nb >> 6, dk0 = nb & 63;
        u16x4 pk;
        pk[0] = f2bf((a[0] + b4.x) * oscale);
        pk[1] = f2bf((a[1] + b4.y) * oscale);
        pk[2] = f2bf((a[2] + b4.z) * oscale);
        pk[3] = f2bf((a[3] + b4.w) * oscale);
        *reinterpret_cast<u16x4*>(&Obf[((((size_t)b * 16 + h) * 1024 + tt) * 64) + dk0]) = pk;
      }
    }
  }
}

// ---------------- out-projection 128x128 BK=64 (R16/R17-proven) ----------------
__global__ __launch_bounds__(256, 1) void gemm_out(const u16* __restrict__ A,
                                                   const u16* __restrict__ Bw,
                                                   const float* __restrict__ bias,
                                                   const float* __restrict__ mask,
                                                   float* __restrict__ Of) {
  constexpr int Kd = 1024;
  __shared__ u16 sA[2][128 * 64];
  __shared__ u16 sB[2][128 * 64];
  const int tid = threadIdx.x;
  const int l = tid & 63, w = tid >> 6;
  const int wm = w >> 1, wn = w & 1;
  const int lr = l & 15, g = l >> 4;
  const int bid = blockIdx.x;
  const int wg = (bid & 7) * 64 + (bid >> 3);
  const int m0 = (wg >> 3) * 128, n0 = (wg & 7) * 128;

  f32x4 acc[4][4];
#pragma unroll
  for (int i = 0; i < 4; i++)
#pragma unroll
    for (int j = 0; j < 4; j++) acc[i][j] = f32x4{0.f, 0.f, 0.f, 0.f};

  int aoff[4], boff[4];
#pragma unroll
  for (int i = 0; i < 4; i++) {
    const int c = i * 256 + tid;
    const int r = c >> 3, cc = (c & 7) ^ (r & 7);
    aoff[i] = r * Kd + cc * 8;
    boff[i] = r * Kd + cc * 8;
  }
  const u16* Abase = A + (size_t)m0 * Kd;
  const u16* Bbase = Bw + (size_t)n0 * Kd;

  auto stage = [&](int buf, int kt) {
#pragma unroll
    for (int i = 0; i < 4; i++)
      GLL16(Abase + kt * 64 + aoff[i], (char*)&sA[buf][0] + (i * 256 + w * 64) * 16);
#pragma unroll
    for (int i = 0; i < 4; i++)
      GLL16(Bbase + kt * 64 + boff[i], (char*)&sB[buf][0] + (i * 256 + w * 64) * 16);
  };

  stage(0, 0);
  for (int t = 0; t < 16; ++t) {
    const int cur = t & 1;
    if (t < 15) {
      stage(cur ^ 1, t + 1);
      asm volatile("s_waitcnt vmcnt(8)" ::: "memory");
    } else {
      asm volatile("s_waitcnt vmcnt(0)" ::: "memory");
    }
    asm volatile("s_barrier" ::: "memory");
#pragma unroll
    for (int ks = 0; ks < 2; ks++) {
      bf16x8 af[4], bfr[4];
#pragma unroll
      for (int mi = 0; mi < 4; mi++) {
        const int row = wm * 64 + mi * 16 + lr;
        af[mi] = *reinterpret_cast<const bf16x8*>(
            (const char*)&sA[cur][0] + row * 128 + ((ks * 64 + g * 16) ^ ((row & 7) << 4)));
      }
#pragma unroll
      for (int ni = 0; ni < 4; ni++) {
        const int row = wn * 64 + ni * 16 + lr;
        bfr[ni] = *reinterpret_cast<const bf16x8*>(
            (const char*)&sB[cur][0] + row * 128 + ((ks * 64 + g * 16) ^ ((row & 7) << 4)));
      }
      __builtin_amdgcn_s_setprio(1);
#pragma unroll
      for (int mi = 0; mi < 4; mi++)
#pragma unroll
        for (int ni = 0; ni < 4; ni++) acc[ni][mi] = mfma16(bfr[ni], af[mi], acc[ni][mi]);
      __builtin_amdgcn_s_setprio(0);
    }
    asm volatile("s_barrier" ::: "memory");
  }

#pragma unroll
  for (int ni = 0; ni < 4; ni++) {
    const int nb = n0 + wn * 64 + ni * 16 + g * 4;
    const float4 b4 = *reinterpret_cast<const float4*>(&bias[nb]);
#pragma unroll
    for (int mi = 0; mi < 4; mi++) {
      const int m = m0 + wm * 64 + mi * 16 + lr;
      const f32x4 a = acc[ni][mi];
      const float mk = mask[m];
      float4 o;
      o.x = (a[0] + b4.x) * mk;
      o.y = (a[1] + b4.y) * mk;
      o.z = (a[2] + b4.z) * mk;
      o.w = (a[3] + b4.w) * mk;
      *reinterpret_cast<float4*>(&Of[(size_t)m * 1024 + nb]) = o;
    }
  }
}

// ---------------- flash attention: 8 waves, V double-buffered, ONE barrier/tile ----------------
// LDS 48KB (sK dbuf 16K + sV dbuf 16K + pbuf 16K) -> 3 blocks/CU (24 waves, up
// from 16). Removing B1 (which sat between softmax and PV) means waves flow
// QK->softmax->PV without intra-tile lockstep; single __syncthreads() per tile
// (its vmcnt(0) drain is cheap: staging had the whole tile's compute to land).
// Race check: all ds_reads consumed by MFMAs pre-barrier => reads complete
// before the barrier; staging for t+1 issued after end-of-(t-1) barrier, when
// all waves finished reading that buffer (R8 per-wave discipline).
__global__ __launch_bounds__(512, 1) void flash_attn(const u16* __restrict__ Qb,
                                                     const u16* __restrict__ Kb,
                                                     const u16* __restrict__ Vt,
                                                     u16* __restrict__ ctx) {
  __shared__ u16 sK[2][64 * 64];
  __shared__ u16 sV[2][64 * 64];
  __shared__ u16 pbuf[8][16 * 64];
  const int tid = threadIdx.x, l = tid & 63, w = tid >> 6;
  const int lr = l & 15, g = l >> 4;
  const int wg = ((blockIdx.x & 7) << 6) + (blockIdx.x >> 3);  // bijective (512%8==0)
  const int qt = wg & 3, bh = wg >> 2;
  const u16* Qh = Qb + (size_t)bh * (Tn * DKn);
  const u16* Kh = Kb + (size_t)bh * (Tn * DKn);
  const u16* Vh = Vt + (size_t)bh * (Tn * DKn);

  bf16x8 aq[2][2];
  int qrow[2];
#pragma unroll
  for (int qg = 0; qg < 2; qg++) {
    qrow[qg] = qt * 256 + w * 32 + qg * 16 + lr;
    aq[qg][0] = *reinterpret_cast<const bf16x8*>(Qh + (size_t)qrow[qg] * 64 + g * 8);
    aq[qg][1] = *reinterpret_cast<const bf16x8*>(Qh + (size_t)qrow[qg] * 64 + 32 + g * 8);
  }

  float mrow[2] = {-1e30f, -1e30f}, lsum[2] = {0.f, 0.f};
  f32x4 of[2][4];
#pragma unroll
  for (int qg = 0; qg < 2; qg++)
#pragma unroll
    for (int c = 0; c < 4; c++) of[qg][c] = f32x4{0.f, 0.f, 0.f, 0.f};

  char* pb = (char*)&pbuf[w][0];
  const int sw = (lr & 7) << 4;
  int wadr[4];
#pragma unroll
  for (int c = 0; c < 4; c++) wadr[c] = lr * 128 + (((c * 16 + g * 4) * 2) ^ sw);
  const int radr0 = lr * 128 + ((g * 16) ^ sw);
  const int radr1 = lr * 128 + ((64 + g * 16) ^ sw);

  // 512 threads stage an 8KB tile in ONE GLL16 each (wave base w*1024, lane x16)
  const int sr = tid >> 3;
  const int sc = (tid & 7) ^ (sr & 7);
  auto stageK = [&](int buf, int kv0) {
    GLL16((const char*)Kh + ((size_t)(kv0 + sr) << 7) + (sc << 4),
          (char*)&sK[buf][0] + w * 1024);
  };
  auto stageV = [&](int buf, int kv0) {
    GLL16((const char*)Vh + ((size_t)sr << 11) + kv0 * 2 + (sc << 4),
          (char*)&sV[buf][0] + w * 1024);
  };

  stageK(0, 0);
  stageV(0, 0);
  __syncthreads();
  int cur = 0;

  for (int t = 0; t < 16; t++) {
    if (t < 15) {
      stageK(cur ^ 1, (t + 1) * 64);
      stageV(cur ^ 1, (t + 1) * 64);
    }
    const char* kb = (const char*)&sK[cur][0];
    const char* vb = (const char*)&sV[cur][0];

    // S^T = K . Q^T for both q-groups (Q pre-scaled by 1/sqrt(dk)*log2e)
    f32x4 sf[2][4];
    __builtin_amdgcn_s_setprio(1);
#pragma unroll
    for (int c = 0; c < 4; c++) {
      const char* kr = kb + (c * 16 + lr) * 128;
      bf16x8 k0 = *reinterpret_cast<const bf16x8*>(kr + ((g * 16) ^ sw));
      bf16x8 k1 = *reinterpret_cast<const bf16x8*>(kr + ((64 + g * 16) ^ sw));
      f32x4 z0 = mfma16(k0, aq[0][0], f32x4{0.f, 0.f, 0.f, 0.f});
      sf[0][c] = mfma16(k1, aq[0][1], z0);
      f32x4 z1 = mfma16(k0, aq[1][0], f32x4{0.f, 0.f, 0.f, 0.f});
      sf[1][c] = mfma16(k1, aq[1][1], z1);
    }
    __builtin_amdgcn_s_setprio(0);

#pragma unroll
    for (int qg = 0; qg < 2; qg++) {
      f32x4 mx4 = sf[qg][0];
#pragma unroll
      for (int c = 1; c < 4; c++)
#pragma unroll
        for (int j = 0; j < 4; j++) mx4[j] = fmaxf(mx4[j], sf[qg][c][j]);
      const float pmax = fmaxf(fmaxf(mx4[0], mx4[1]), fmaxf(mx4[2], mx4[3]));
      if (__any(pmax > mrow[qg] + 8.0f)) {
        float mx = pmax;
        mx = fmaxf(mx, __shfl_xor(mx, 16));
        mx = fmaxf(mx, __shfl_xor(mx, 32));
        const float mn = fmaxf(mrow[qg], mx);
        const float alpha = fast_exp2(mrow[qg] - mn);
        mrow[qg] = mn;
        lsum[qg] *= alpha;
#pragma unroll
        for (int c = 0; c < 4; c++)
#pragma unroll
          for (int j = 0; j < 4; j++) of[qg][c][j] *= alpha;
      }
      const float mn = mrow[qg];
      float rs = 0.f;
#pragma unroll
      for (int c = 0; c < 4; c++)
#pragma unroll
        for (int j = 0; j < 4; j++) {
          float pp = fast_exp2(sf[qg][c][j] - mn);
          sf[qg][c][j] = pp;
          rs += pp;
        }
      lsum[qg] += rs;

      // P -> per-wave LDS rows [q=lr][kv] (b64, swizzled), re-read as B-frags
#pragma unroll
      for (int c = 0; c < 4; c++) {
        uint2 pk;
        pk.x = cvt_pk_bf16(sf[qg][c][0], sf[qg][c][1]);
        pk.y = cvt_pk_bf16(sf[qg][c][2], sf[qg][c][3]);
        *reinterpret_cast<uint2*>(pb + wadr[c]) = pk;
      }
      const bf16x8 ap0 = *reinterpret_cast<const bf16x8*>(pb + radr0);
      const bf16x8 ap1 = *reinterpret_cast<const bf16x8*>(pb + radr1);

      // O^T += V^T . P^T  (no barrier between softmax and PV: V is dbuf'd)
      __builtin_amdgcn_s_setprio(1);
#pragma unroll
      for (int d0 = 0; d0 < 4; d0++) {
        const char* vr = vb + (d0 * 16 + lr) * 128;
        bf16x8 v0 = *reinterpret_cast<const bf16x8*>(vr + ((g * 16) ^ sw));
        bf16x8 v1 = *reinterpret_cast<const bf16x8*>(vr + ((64 + g * 16) ^ sw));
        f32x4 z = mfma16(v0, ap0, of[qg][d0]);
        of[qg][d0] = mfma16(v1, ap1, z);
      }
      __builtin_amdgcn_s_setprio(0);
    }

    __syncthreads();  // single barrier: tile-(t+1) staging drained & visible;
                      // all waves done with tile-t buffers before t+1 staging of t+2
    cur ^= 1;
  }

  const int b = bh >> 4, h = bh & 15;
#pragma unroll
  for (int qg = 0; qg < 2; qg++) {
    float ls = lsum[qg];
    ls += __shfl_xor(ls, 16);
    ls += __shfl_xor(ls, 32);
    const float inv = 1.0f / ls;
    const size_t base = ((size_t)b * 1024 + qrow[qg]) * 1024 + h * 64;
#pragma unroll
    for (int d0 = 0; d0 < 4; d0++) {
      uint2 pk;
      pk.x = cvt_pk_bf16(of[qg][d0][0] * inv, of[qg][d0][1] * inv);
      pk.y = cvt_pk_bf16(of[qg][d0][2] * inv, of[qg][d0][3] * inv);
      *reinterpret_cast<uint2*>(ctx + base + d0 * 16 + g * 4) = pk;
    }
  }
}

// ---------------- launch ----------------
extern "C" void kernel_launch(void* const* d_in, const int* in_sizes, int n_in,
                              void* d_out, int out_size, void* d_ws, size_t ws_size,
                              hipStream_t stream) {
  const float* query = (const float*)d_in[0];
  const float* key = (const float*)d_in[1];
  const float* value = (const float*)d_in[2];
  const float* mask = (const float*)d_in[3];
  const float* Wq = (const float*)d_in[4];
  const float* bq = (const float*)d_in[5];
  const float* Wk = (const float*)d_in[6];
  const float* bk = (const float*)d_in[7];
  const float* Wv = (const float*)d_in[8];
  const float* bv = (const float*)d_in[9];
  const float* Wo = (const float*)d_in[10];
  const float* bo = (const float*)d_in[11];
  (void)in_sizes; (void)n_in; (void)out_size; (void)ws_size;

  u16* ws = (u16*)d_ws;
  const size_t MB8 = (size_t)8 << 20;  // 8M u16 = 16 MB
  u16* ctx = ws;
  u16* Wqb = ws + 3 * MB8;
  u16* Wkb = Wqb + (1 << 20);
  u16* Wvb = Wkb + (1 << 20);
  u16* Wob = Wvb + (1 << 20);
  u16* Qb = Wob + (1 << 20);
  u16* Kb = Qb + MB8;
  u16* Vtb = Kb + MB8;

  cvt4<<<2048, 256, 0, stream>>>(Wq, Wk, Wv, Wo, Wqb, Wkb, Wvb, Wob);

  const float SC = 0.125f * 1.44269504089f;  // 1/sqrt(DK) * log2(e)
  const int ng = (Mtot / 128) * (Fn / 128);  // 512 blocks
  gemm8f<0><<<ng, 256, 0, stream>>>(query, Wqb, bq, Qb, SC);
  gemm8f<0><<<ng, 256, 0, stream>>>(key, Wkb, bk, Kb, 1.0f);
  gemm8f<1><<<ng, 256, 0, stream>>>(value, Wvb, bv, Vtb, 1.0f);

  flash_attn<<<Bn * Hn * (Tn / 256), 512, 0, stream>>>(Qb, Kb, Vtb, ctx);

  gemm_out<<<ng, 256, 0, stream>>>(ctx, Wob, bo, mask, (float*)d_out);
}

// Round 20
// 170.464 us; speedup vs baseline: 1.1906x; 1.0180x over previous
//
#include <hip/hip_runtime.h>
#include <hip/hip_bf16.h>

typedef unsigned short u16;
typedef unsigned int u32;
typedef __attribute__((ext_vector_type(8))) short bf16x8;
typedef __attribute__((ext_vector_type(8))) unsigned short u16x8;
typedef __attribute__((ext_vector_type(4))) unsigned short u16x4;
typedef __attribute__((ext_vector_type(4))) float f32x4;

#define DEVI __device__ __forceinline__

static constexpr int Bn = 8, Tn = 1024, Fn = 1024, Hn = 16, DKn = 64;
static constexpr int Mtot = Bn * Tn;  // 8192

DEVI u16 f2bf(float x) {
  unsigned u = __builtin_bit_cast(unsigned, x);
  u += 0x7fffu + ((u >> 16) & 1u);
  return (u16)(u >> 16);
}

DEVI u32 cvt_pk_bf16(float lo, float hi) {
  u32 r;
  asm("v_cvt_pk_bf16_f32 %0, %1, %2" : "=v"(r) : "v"(lo), "v"(hi));
  return r;
}

DEVI float fast_exp2(float x) { return __builtin_amdgcn_exp2f(x); }  // bare v_exp_f32

DEVI f32x4 mfma16(bf16x8 a, bf16x8 b, f32x4 c) {
  return __builtin_amdgcn_mfma_f32_16x16x32_bf16(a, b, c, 0, 0, 0);
}

typedef const __attribute__((address_space(1))) void GAS;
typedef __attribute__((address_space(3))) void LAS;
#define GLL16(gp, lp) __builtin_amdgcn_global_load_lds((GAS*)(gp), (LAS*)(lp), 16, 0, 0)

// ---------------- fp32 -> bf16 conversion (weights only; X is fused into GEMM) ----------------
DEVI void cvt_chunk(const float* __restrict__ in, u16* __restrict__ out, int i) {
  const float4* p = reinterpret_cast<const float4*>(in + i);
  float4 a = p[0], b = p[1];
  float v[8] = {a.x, a.y, a.z, a.w, b.x, b.y, b.z, b.w};
  u16x8 r;
#pragma unroll
  for (int j = 0; j < 8; j++) r[j] = f2bf(v[j]);
  *reinterpret_cast<u16x8*>(out + i) = r;
}

__global__ __launch_bounds__(256) void cvt4(const float* __restrict__ a, const float* __restrict__ b,
                                            const float* __restrict__ c, const float* __restrict__ e,
                                            u16* __restrict__ oa, u16* __restrict__ ob,
                                            u16* __restrict__ oc, u16* __restrict__ oe) {
  const int id = blockIdx.x * 256 + threadIdx.x;
  const int seg = id >> 17;
  const int off = (id & 131071) * 8;
  const float* s = seg == 0 ? a : (seg == 1 ? b : (seg == 2 ? c : e));
  u16* d = seg == 0 ? oa : (seg == 1 ? ob : (seg == 2 ? oc : oe));
  cvt_chunk(s, d, off);
}

// ============ 128x128 BK=64 fused-convert Q+K projection (grid.y selects tensor) ============
// R17-proven core; blockIdx.y picks ONLY kernel arguments (A/bias/out/oscale) --
// wave-uniform scalar selects on a SINGLE template instantiation (avoids R10's
// dual-instantiation regression). Fusing Q&K into one dispatch backfills the
// inter-kernel tail (two 512-block grids -> one 1024-block grid).
__global__ __launch_bounds__(256, 1) void gemm_qk(
    const float* __restrict__ Aq, const float* __restrict__ Ak,
    const u16* __restrict__ Wqb, const u16* __restrict__ Wkb,
    const float* __restrict__ bq, const float* __restrict__ bk,
    u16* __restrict__ Qo, u16* __restrict__ Ko, float SC) {
  constexpr int Kd = 1024;
  __shared__ u16 sA[2][128 * 64];
  __shared__ u16 sB[2][128 * 64];
  const int tid = threadIdx.x;
  const int l = tid & 63, w = tid >> 6;
  const int wm = w >> 1, wn = w & 1;
  const int lr = l & 15, g = l >> 4;
  const int p = blockIdx.y;
  const float* A = p == 0 ? Aq : Ak;
  const u16* Bw = p == 0 ? Wqb : Wkb;
  const float* bias = p == 0 ? bq : bk;
  u16* Obf = p == 0 ? Qo : Ko;
  const float oscale = p == 0 ? SC : 1.0f;
  const int bid = blockIdx.x;
  const int wg = (bid & 7) * 64 + (bid >> 3);  // bijective XCD swizzle (512%8==0)
  const int m0 = (wg >> 3) * 128, n0 = (wg & 7) * 128;

  f32x4 acc[4][4];
#pragma unroll
  for (int i = 0; i < 4; i++)
#pragma unroll
    for (int j = 0; j < 4; j++) acc[i][j] = f32x4{0.f, 0.f, 0.f, 0.f};

  int aoffF[4], awb[4];
#pragma unroll
  for (int i = 0; i < 4; i++) {
    const int c = i * 256 + tid;
    const int r = c >> 3, cc = c & 7;
    aoffF[i] = r * Kd + cc * 8;
    awb[i] = r * 128 + ((cc ^ (r & 7)) << 4);
  }
  int boff[4];
#pragma unroll
  for (int i = 0; i < 4; i++) {
    const int c = i * 256 + tid;
    const int r = c >> 3, cc = (c & 7) ^ (r & 7);
    boff[i] = r * Kd + cc * 8;
  }
  const float* Af = A + (size_t)m0 * Kd;
  const u16* Bbase = Bw + (size_t)n0 * Kd;

  float4 ra[4][2];
  auto loadA = [&](int kt) {
#pragma unroll
    for (int i = 0; i < 4; i++) {
      const float* s = Af + kt * 64 + aoffF[i];
      ra[i][0] = *reinterpret_cast<const float4*>(s);
      ra[i][1] = *reinterpret_cast<const float4*>(s + 4);
    }
  };
  auto writeA = [&](int buf) {
#pragma unroll
    for (int i = 0; i < 4; i++) {
      uint4 pk;
      pk.x = cvt_pk_bf16(ra[i][0].x, ra[i][0].y);
      pk.y = cvt_pk_bf16(ra[i][0].z, ra[i][0].w);
      pk.z = cvt_pk_bf16(ra[i][1].x, ra[i][1].y);
      pk.w = cvt_pk_bf16(ra[i][1].z, ra[i][1].w);
      *reinterpret_cast<uint4*>((char*)&sA[buf][0] + awb[i]) = pk;
    }
  };
  auto stageB = [&](int buf, int kt) {
#pragma unroll
    for (int i = 0; i < 4; i++)
      GLL16(Bbase + kt * 64 + boff[i], (char*)&sB[buf][0] + (i * 256 + w * 64) * 16);
  };

  loadA(0);
  stageB(0, 0);
  writeA(0);
  for (int t = 0; t < 16; ++t) {
    const int cur = t & 1;
    if (t < 15) {
      loadA(t + 1);
      stageB(cur ^ 1, t + 1);
      asm volatile("s_waitcnt vmcnt(12) lgkmcnt(0)" ::: "memory");
    } else {
      asm volatile("s_waitcnt vmcnt(0) lgkmcnt(0)" ::: "memory");
    }
    asm volatile("s_barrier" ::: "memory");
#pragma unroll
    for (int ks = 0; ks < 2; ks++) {
      bf16x8 af[4], bfr[4];
#pragma unroll
      for (int mi = 0; mi < 4; mi++) {
        const int row = wm * 64 + mi * 16 + lr;
        af[mi] = *reinterpret_cast<const bf16x8*>(
            (const char*)&sA[cur][0] + row * 128 + ((ks * 64 + g * 16) ^ ((row & 7) << 4)));
      }
#pragma unroll
      for (int ni = 0; ni < 4; ni++) {
        const int row = wn * 64 + ni * 16 + lr;
        bfr[ni] = *reinterpret_cast<const bf16x8*>(
            (const char*)&sB[cur][0] + row * 128 + ((ks * 64 + g * 16) ^ ((row & 7) << 4)));
      }
      __builtin_amdgcn_s_setprio(1);
#pragma unroll
      for (int mi = 0; mi < 4; mi++)
#pragma unroll
        for (int ni = 0; ni < 4; ni++) acc[ni][mi] = mfma16(bfr[ni], af[mi], acc[ni][mi]);
      __builtin_amdgcn_s_setprio(0);
    }
    if (t < 15) writeA(cur ^ 1);
    asm volatile("s_barrier" ::: "memory");
  }

  // (B,H,T,DK): rows=n via (g,j) -> 4 consecutive dk per lane
#pragma unroll
  for (int ni = 0; ni < 4; ni++) {
    const int nb = n0 + wn * 64 + ni * 16 + g * 4;
    const float4 b4 = *reinterpret_cast<const float4*>(&bias[nb]);
#pragma unroll
    for (int mi = 0; mi < 4; mi++) {
      const int m = m0 + wm * 64 + mi * 16 + lr;
      const f32x4 a = acc[ni][mi];
      const int b = m >> 10, tt = m & 1023;
      const int h = nb >> 6, dk0 = nb & 63;
      u16x4 pk;
      pk[0] = f2bf((a[0] + b4.x) * oscale);
      pk[1] = f2bf((a[1] + b4.y) * oscale);
      pk[2] = f2bf((a[2] + b4.z) * oscale);
      pk[3] = f2bf((a[3] + b4.w) * oscale);
      *reinterpret_cast<u16x4*>(&Obf[((((size_t)b * 16 + h) * 1024 + tt) * 64) + dk0]) = pk;
    }
  }
}

// ============ V projection (R17 MODE 1: unswapped acc, V^T output) ============
__global__ __launch_bounds__(256, 1) void gemm_v(const float* __restrict__ A,
                                                 const u16* __restrict__ Bw,
                                                 const float* __restrict__ bias,
                                                 u16* __restrict__ Obf) {
  constexpr int Kd = 1024;
  __shared__ u16 sA[2][128 * 64];
  __shared__ u16 sB[2][128 * 64];
  const int tid = threadIdx.x;
  const int l = tid & 63, w = tid >> 6;
  const int wm = w >> 1, wn = w & 1;
  const int lr = l & 15, g = l >> 4;
  const int bid = blockIdx.x;
  const int wg = (bid & 7) * 64 + (bid >> 3);
  const int m0 = (wg >> 3) * 128, n0 = (wg & 7) * 128;

  f32x4 acc[4][4];
#pragma unroll
  for (int i = 0; i < 4; i++)
#pragma unroll
    for (int j = 0; j < 4; j++) acc[i][j] = f32x4{0.f, 0.f, 0.f, 0.f};

  int aoffF[4], awb[4];
#pragma unroll
  for (int i = 0; i < 4; i++) {
    const int c = i * 256 + tid;
    const int r = c >> 3, cc = c & 7;
    aoffF[i] = r * Kd + cc * 8;
    awb[i] = r * 128 + ((cc ^ (r & 7)) << 4);
  }
  int boff[4];
#pragma unroll
  for (int i = 0; i < 4; i++) {
    const int c = i * 256 + tid;
    const int r = c >> 3, cc = (c & 7) ^ (r & 7);
    boff[i] = r * Kd + cc * 8;
  }
  const float* Af = A + (size_t)m0 * Kd;
  const u16* Bbase = Bw + (size_t)n0 * Kd;

  float4 ra[4][2];
  auto loadA = [&](int kt) {
#pragma unroll
    for (int i = 0; i < 4; i++) {
      const float* s = Af + kt * 64 + aoffF[i];
      ra[i][0] = *reinterpret_cast<const float4*>(s);
      ra[i][1] = *reinterpret_cast<const float4*>(s + 4);
    }
  };
  auto writeA = [&](int buf) {
#pragma unroll
    for (int i = 0; i < 4; i++) {
      uint4 pk;
      pk.x = cvt_pk_bf16(ra[i][0].x, ra[i][0].y);
      pk.y = cvt_pk_bf16(ra[i][0].z, ra[i][0].w);
      pk.z = cvt_pk_bf16(ra[i][1].x, ra[i][1].y);
      pk.w = cvt_pk_bf16(ra[i][1].z, ra[i][1].w);
      *reinterpret_cast<uint4*>((char*)&sA[buf][0] + awb[i]) = pk;
    }
  };
  auto stageB = [&](int buf, int kt) {
#pragma unroll
    for (int i = 0; i < 4; i++)
      GLL16(Bbase + kt * 64 + boff[i], (char*)&sB[buf][0] + (i * 256 + w * 64) * 16);
  };

  loadA(0);
  stageB(0, 0);
  writeA(0);
  for (int t = 0; t < 16; ++t) {
    const int cur = t & 1;
    if (t < 15) {
      loadA(t + 1);
      stageB(cur ^ 1, t + 1);
      asm volatile("s_waitcnt vmcnt(12) lgkmcnt(0)" ::: "memory");
    } else {
      asm volatile("s_waitcnt vmcnt(0) lgkmcnt(0)" ::: "memory");
    }
    asm volatile("s_barrier" ::: "memory");
#pragma unroll
    for (int ks = 0; ks < 2; ks++) {
      bf16x8 af[4], bfr[4];
#pragma unroll
      for (int mi = 0; mi < 4; mi++) {
        const int row = wm * 64 + mi * 16 + lr;
        af[mi] = *reinterpret_cast<const bf16x8*>(
            (const char*)&sA[cur][0] + row * 128 + ((ks * 64 + g * 16) ^ ((row & 7) << 4)));
      }
#pragma unroll
      for (int ni = 0; ni < 4; ni++) {
        const int row = wn * 64 + ni * 16 + lr;
        bfr[ni] = *reinterpret_cast<const bf16x8*>(
            (const char*)&sB[cur][0] + row * 128 + ((ks * 64 + g * 16) ^ ((row & 7) << 4)));
      }
      __builtin_amdgcn_s_setprio(1);
#pragma unroll
      for (int mi = 0; mi < 4; mi++)
#pragma unroll
        for (int ni = 0; ni < 4; ni++) acc[mi][ni] = mfma16(af[mi], bfr[ni], acc[mi][ni]);
      __builtin_amdgcn_s_setprio(0);
    }
    if (t < 15) writeA(cur ^ 1);
    asm volatile("s_barrier" ::: "memory");
  }

  // V^T (B,H,DK,T): rows=m via (g,j) -> u16x4 along t
#pragma unroll
  for (int ni = 0; ni < 4; ni++) {
    const int n = n0 + wn * 64 + ni * 16 + lr;
    const float bv = bias[n];
    const int h = n >> 6, dk = n & 63;
#pragma unroll
    for (int mi = 0; mi < 4; mi++) {
      const int mb = m0 + wm * 64 + mi * 16 + g * 4;
      u16x4 pk;
#pragma unroll
      for (int j = 0; j < 4; j++) pk[j] = f2bf(acc[mi][ni][j] + bv);
      const int b = mb >> 10, tt = mb & 1023;
      size_t idx = (((size_t)b * 16 + h) * 64 + dk) * 1024 + tt;
      *reinterpret_cast<u16x4*>(Obf + idx) = pk;
    }
  }
}

// ---------------- out-projection 128x128 BK=64 (R16/R17-proven) ----------------
__global__ __launch_bounds__(256, 1) void gemm_out(const u16* __restrict__ A,
                                                   const u16* __restrict__ Bw,
                                                   const float* __restrict__ bias,
                                                   const float* __restrict__ mask,
                                                   float* __restrict__ Of) {
  constexpr int Kd = 1024;
  __shared__ u16 sA[2][128 * 64];
  __shared__ u16 sB[2][128 * 64];
  const int tid = threadIdx.x;
  const int l = tid & 63, w = tid >> 6;
  const int wm = w >> 1, wn = w & 1;
  const int lr = l & 15, g = l >> 4;
  const int bid = blockIdx.x;
  const int wg = (bid & 7) * 64 + (bid >> 3);
  const int m0 = (wg >> 3) * 128, n0 = (wg & 7) * 128;

  f32x4 acc[4][4];
#pragma unroll
  for (int i = 0; i < 4; i++)
#pragma unroll
    for (int j = 0; j < 4; j++) acc[i][j] = f32x4{0.f, 0.f, 0.f, 0.f};

  int aoff[4], boff[4];
#pragma unroll
  for (int i = 0; i < 4; i++) {
    const int c = i * 256 + tid;
    const int r = c >> 3, cc = (c & 7) ^ (r & 7);
    aoff[i] = r * Kd + cc * 8;
    boff[i] = r * Kd + cc * 8;
  }
  const u16* Abase = A + (size_t)m0 * Kd;
  const u16* Bbase = Bw + (size_t)n0 * Kd;

  auto stage = [&](int buf, int kt) {
#pragma unroll
    for (int i = 0; i < 4; i++)
      GLL16(Abase + kt * 64 + aoff[i], (char*)&sA[buf][0] + (i * 256 + w * 64) * 16);
#pragma unroll
    for (int i = 0; i < 4; i++)
      GLL16(Bbase + kt * 64 + boff[i], (char*)&sB[buf][0] + (i * 256 + w * 64) * 16);
  };

  stage(0, 0);
  for (int t = 0; t < 16; ++t) {
    const int cur = t & 1;
    if (t < 15) {
      stage(cur ^ 1, t + 1);
      asm volatile("s_waitcnt vmcnt(8)" ::: "memory");
    } else {
      asm volatile("s_waitcnt vmcnt(0)" ::: "memory");
    }
    asm volatile("s_barrier" ::: "memory");
#pragma unroll
    for (int ks = 0; ks < 2; ks++) {
      bf16x8 af[4], bfr[4];
#pragma unroll
      for (int mi = 0; mi < 4; mi++) {
        const int row = wm * 64 + mi * 16 + lr;
        af[mi] = *reinterpret_cast<const bf16x8*>(
            (const char*)&sA[cur][0] + row * 128 + ((ks * 64 + g * 16) ^ ((row & 7) << 4)));
      }
#pragma unroll
      for (int ni = 0; ni < 4; ni++) {
        const int row = wn * 64 + ni * 16 + lr;
        bfr[ni] = *reinterpret_cast<const bf16x8*>(
            (const char*)&sB[cur][0] + row * 128 + ((ks * 64 + g * 16) ^ ((row & 7) << 4)));
      }
      __builtin_amdgcn_s_setprio(1);
#pragma unroll
      for (int mi = 0; mi < 4; mi++)
#pragma unroll
        for (int ni = 0; ni < 4; ni++) acc[ni][mi] = mfma16(bfr[ni], af[mi], acc[ni][mi]);
      __builtin_amdgcn_s_setprio(0);
    }
    asm volatile("s_barrier" ::: "memory");
  }

#pragma unroll
  for (int ni = 0; ni < 4; ni++) {
    const int nb = n0 + wn * 64 + ni * 16 + g * 4;
    const float4 b4 = *reinterpret_cast<const float4*>(&bias[nb]);
#pragma unroll
    for (int mi = 0; mi < 4; mi++) {
      const int m = m0 + wm * 64 + mi * 16 + lr;
      const f32x4 a = acc[ni][mi];
      const float mk = mask[m];
      float4 o;
      o.x = (a[0] + b4.x) * mk;
      o.y = (a[1] + b4.y) * mk;
      o.z = (a[2] + b4.z) * mk;
      o.w = (a[3] + b4.w) * mk;
      *reinterpret_cast<float4*>(&Of[(size_t)m * 1024 + nb]) = o;
    }
  }
}

// ---------------- flash attention (R17 frozen: 8 waves x 32 q-rows, grid 512) ----------------
__global__ __launch_bounds__(512, 1) void flash_attn(const u16* __restrict__ Qb,
                                                     const u16* __restrict__ Kb,
                                                     const u16* __restrict__ Vt,
                                                     u16* __restrict__ ctx) {
  __shared__ u16 sK[2][64 * 64];
  __shared__ u16 sV[64 * 64];
  __shared__ u16 pbuf[8][16 * 64];
  const int tid = threadIdx.x, l = tid & 63, w = tid >> 6;
  const int lr = l & 15, g = l >> 4;
  const int wg = ((blockIdx.x & 7) << 6) + (blockIdx.x >> 3);  // bijective (512%8==0)
  const int qt = wg & 3, bh = wg >> 2;
  const u16* Qh = Qb + (size_t)bh * (Tn * DKn);
  const u16* Kh = Kb + (size_t)bh * (Tn * DKn);
  const u16* Vh = Vt + (size_t)bh * (Tn * DKn);

  bf16x8 aq[2][2];
  int qrow[2];
#pragma unroll
  for (int qg = 0; qg < 2; qg++) {
    qrow[qg] = qt * 256 + w * 32 + qg * 16 + lr;
    aq[qg][0] = *reinterpret_cast<const bf16x8*>(Qh + (size_t)qrow[qg] * 64 + g * 8);
    aq[qg][1] = *reinterpret_cast<const bf16x8*>(Qh + (size_t)qrow[qg] * 64 + 32 + g * 8);
  }

  float mrow[2] = {-1e30f, -1e30f}, lsum[2] = {0.f, 0.f};
  f32x4 of[2][4];
#pragma unroll
  for (int qg = 0; qg < 2; qg++)
#pragma unroll
    for (int c = 0; c < 4; c++) of[qg][c] = f32x4{0.f, 0.f, 0.f, 0.f};

  char* pb = (char*)&pbuf[w][0];
  const int sw = (lr & 7) << 4;
  int wadr[4];
#pragma unroll
  for (int c = 0; c < 4; c++) wadr[c] = lr * 128 + (((c * 16 + g * 4) * 2) ^ sw);
  const int radr0 = lr * 128 + ((g * 16) ^ sw);
  const int radr1 = lr * 128 + ((64 + g * 16) ^ sw);

  const int sr = tid >> 3;
  const int sc = (tid & 7) ^ (sr & 7);
  auto stageK = [&](int buf, int kv0) {
    GLL16((const char*)Kh + ((size_t)(kv0 + sr) << 7) + (sc << 4),
          (char*)&sK[buf][0] + w * 1024);
  };
  auto stageV = [&](int kv0) {
    GLL16((const char*)Vh + ((size_t)sr << 11) + kv0 * 2 + (sc << 4),
          (char*)&sV[0] + w * 1024);
  };

  stageK(0, 0);
  stageV(0);
  __syncthreads();
  int cur = 0;

  for (int t = 0; t < 16; t++) {
    if (t < 15) stageK(cur ^ 1, (t + 1) * 64);
    const char* kb = (const char*)&sK[cur][0];
    const char* vb = (const char*)&sV[0];

    f32x4 sf[2][4];
    __builtin_amdgcn_s_setprio(1);
#pragma unroll
    for (int c = 0; c < 4; c++) {
      const char* kr = kb + (c * 16 + lr) * 128;
      bf16x8 k0 = *reinterpret_cast<const bf16x8*>(kr + ((g * 16) ^ sw));
      bf16x8 k1 = *reinterpret_cast<const bf16x8*>(kr + ((64 + g * 16) ^ sw));
      f32x4 z0 = mfma16(k0, aq[0][0], f32x4{0.f, 0.f, 0.f, 0.f});
      sf[0][c] = mfma16(k1, aq[0][1], z0);
      f32x4 z1 = mfma16(k0, aq[1][0], f32x4{0.f, 0.f, 0.f, 0.f});
      sf[1][c] = mfma16(k1, aq[1][1], z1);
    }
    __builtin_amdgcn_s_setprio(0);

    bf16x8 ap[2][2];
#pragma unroll
    for (int qg = 0; qg < 2; qg++) {
      f32x4 mx4 = sf[qg][0];
#pragma unroll
      for (int c = 1; c < 4; c++)
#pragma unroll
        for (int j = 0; j < 4; j++) mx4[j] = fmaxf(mx4[j], sf[qg][c][j]);
      const float pmax = fmaxf(fmaxf(mx4[0], mx4[1]), fmaxf(mx4[2], mx4[3]));
      if (__any(pmax > mrow[qg] + 8.0f)) {
        float mx = pmax;
        mx = fmaxf(mx, __shfl_xor(mx, 16));
        mx = fmaxf(mx, __shfl_xor(mx, 32));
        const float mn = fmaxf(mrow[qg], mx);
        const float alpha = fast_exp2(mrow[qg] - mn);
        mrow[qg] = mn;
        lsum[qg] *= alpha;
#pragma unroll
        for (int c = 0; c < 4; c++)
#pragma unroll
          for (int j = 0; j < 4; j++) of[qg][c][j] *= alpha;
      }
      const float mn = mrow[qg];
      float rs = 0.f;
#pragma unroll
      for (int c = 0; c < 4; c++)
#pragma unroll
        for (int j = 0; j < 4; j++) {
          float pp = fast_exp2(sf[qg][c][j] - mn);
          sf[qg][c][j] = pp;
          rs += pp;
        }
      lsum[qg] += rs;

#pragma unroll
      for (int c = 0; c < 4; c++) {
        uint2 pk;
        pk.x = cvt_pk_bf16(sf[qg][c][0], sf[qg][c][1]);
        pk.y = cvt_pk_bf16(sf[qg][c][2], sf[qg][c][3]);
        *reinterpret_cast<uint2*>(pb + wadr[c]) = pk;
      }
      ap[qg][0] = *reinterpret_cast<const bf16x8*>(pb + radr0);
      ap[qg][1] = *reinterpret_cast<const bf16x8*>(pb + radr1);
    }

    __syncthreads();  // B1: sV(t) writes drained & visible

    __builtin_amdgcn_s_setprio(1);
#pragma unroll
    for (int d0 = 0; d0 < 4; d0++) {
      const char* vr = vb + (d0 * 16 + lr) * 128;
      bf16x8 v0 = *reinterpret_cast<const bf16x8*>(vr + ((g * 16) ^ sw));
      bf16x8 v1 = *reinterpret_cast<const bf16x8*>(vr + ((64 + g * 16) ^ sw));
#pragma unroll
      for (int qg = 0; qg < 2; qg++) {
        f32x4 z = mfma16(v0, ap[qg][0], of[qg][d0]);
        of[qg][d0] = mfma16(v1, ap[qg][1], z);
      }
    }
    __builtin_amdgcn_s_setprio(0);

    __syncthreads();  // B2: all waves done reading sV(t)/sK[cur]
    if (t < 15) stageV((t + 1) * 64);
    cur ^= 1;
  }

  const int b = bh >> 4, h = bh & 15;
#pragma unroll
  for (int qg = 0; qg < 2; qg++) {
    float ls = lsum[qg];
    ls += __shfl_xor(ls, 16);
    ls += __shfl_xor(ls, 32);
    const float inv = 1.0f / ls;
    const size_t base = ((size_t)b * 1024 + qrow[qg]) * 1024 + h * 64;
#pragma unroll
    for (int d0 = 0; d0 < 4; d0++) {
      uint2 pk;
      pk.x = cvt_pk_bf16(of[qg][d0][0] * inv, of[qg][d0][1] * inv);
      pk.y = cvt_pk_bf16(of[qg][d0][2] * inv, of[qg][d0][3] * inv);
      *reinterpret_cast<uint2*>(ctx + base + d0 * 16 + g * 4) = pk;
    }
  }
}

// ---------------- launch ----------------
extern "C" void kernel_launch(void* const* d_in, const int* in_sizes, int n_in,
                              void* d_out, int out_size, void* d_ws, size_t ws_size,
                              hipStream_t stream) {
  const float* query = (const float*)d_in[0];
  const float* key = (const float*)d_in[1];
  const float* value = (const float*)d_in[2];
  const float* mask = (const float*)d_in[3];
  const float* Wq = (const float*)d_in[4];
  const float* bq = (const float*)d_in[5];
  const float* Wk = (const float*)d_in[6];
  const float* bk = (const float*)d_in[7];
  const float* Wv = (const float*)d_in[8];
  const float* bv = (const float*)d_in[9];
  const float* Wo = (const float*)d_in[10];
  const float* bo = (const float*)d_in[11];
  (void)in_sizes; (void)n_in; (void)out_size; (void)ws_size;

  u16* ws = (u16*)d_ws;
  const size_t MB8 = (size_t)8 << 20;  // 8M u16 = 16 MB
  u16* ctx = ws;
  u16* Wqb = ws + 3 * MB8;
  u16* Wkb = Wqb + (1 << 20);
  u16* Wvb = Wkb + (1 << 20);
  u16* Wob = Wvb + (1 << 20);
  u16* Qb = Wob + (1 << 20);
  u16* Kb = Qb + MB8;
  u16* Vtb = Kb + MB8;

  cvt4<<<2048, 256, 0, stream>>>(Wq, Wk, Wv, Wo, Wqb, Wkb, Wvb, Wob);

  const float SC = 0.125f * 1.44269504089f;  // 1/sqrt(DK) * log2(e)
  const int ng = (Mtot / 128) * (Fn / 128);  // 512 blocks
  gemm_qk<<<dim3(ng, 2), 256, 0, stream>>>(query, key, Wqb, Wkb, bq, bk, Qb, Kb, SC);
  gemm_v<<<ng, 256, 0, stream>>>(value, Wvb, bv, Vtb);

  flash_attn<<<Bn * Hn * (Tn / 256), 512, 0, stream>>>(Qb, Kb, Vtb, ctx);

  gemm_out<<<ng, 256, 0, stream>>>(ctx, Wob, bo, mask, (float*)d_out);
}